// Round 1
// baseline (126.029 us; speedup 1.0000x reference)
//
#include <hip/hip_runtime.h>
#include <cstdint>
#include <cstddef>

#define SCALE 0.42044820762685725f  // 32^(-1/4)

typedef __attribute__((ext_vector_type(8))) short short8;
typedef __attribute__((ext_vector_type(4))) short short4v;
typedef __attribute__((ext_vector_type(4))) float f32x4;

__device__ __forceinline__ unsigned short f2bf(float f) {
    unsigned int u = __builtin_bit_cast(unsigned int, f);
    u = (u + 0x7fffu + ((u >> 16) & 1u)) >> 16;   // RNE
    return (unsigned short)u;
}
__device__ __forceinline__ float bf2f(unsigned short h) {
    unsigned int u = ((unsigned int)h) << 16;
    return __builtin_bit_cast(float, u);
}

// ---------------- prepack: proj_w fp32 -> bf16 in MFMA fragment order ----------------
// ws layout: [0, 131072) ushort : WkvP, A-frag order:
//   idx = ((mtg*8 + ks)*64 + lane)*8 + j  <->  W[256 + mtg*16 + (lane&15)][ks*32 + (lane>>4)*8 + j]
// [131072, 196608) ushort : WqT[c*256 + o] = W[o][c]   (o < 256)
__global__ __launch_bounds__(256) void prepack_w(const float* __restrict__ w,
                                                 unsigned short* __restrict__ wp) {
    int gid = blockIdx.x * 256 + threadIdx.x;
    if (gid < 16384) {
        int lane = gid & 63;
        int ks   = (gid >> 6) & 7;
        int mtg  = gid >> 9;
        int row  = 256 + mtg * 16 + (lane & 15);
        int k0   = ks * 32 + (lane >> 4) * 8;
        const float* src = w + row * 256 + k0;
        short8 v;
#pragma unroll
        for (int j = 0; j < 8; ++j) v[j] = (short)f2bf(src[j]);
        *reinterpret_cast<short8*>(wp + (size_t)gid * 8) = v;
    } else {
        int u = gid - 16384;          // < 65536
        int c = u >> 8, o = u & 255;
        wp[131072 + u] = f2bf(w[o * 256 + c]);
    }
}

// ---------------- main fused kernel: one WG per 8x8 tile ----------------
template <bool PRE>
__global__ __launch_bounds__(256, 2) void attn_fused(
        const float* __restrict__ x, const float* __restrict__ proj_w,
        const float* __restrict__ proj_b, const float* __restrict__ pos,
        const unsigned short* __restrict__ wpack, float* __restrict__ out) {
    // s_main: union of x-tile (bf16 [p=64][c=256] swizzled, 32768B)
    //         and key-LDS  (bf16 [k=64][m=260] padded,       33280B)
    __shared__ __align__(16) unsigned char s_main[33280];
    __shared__ float s_bias[512];   // proj_b[256..768)
    __shared__ float s_qs[256];     // scale*(q + bias)
    __shared__ float s_attn[512];   // [head][k]

    const int t    = threadIdx.x;
    const int lane = t & 63;
    const int wave = t >> 6;
    const int l15  = lane & 15;
    const int l4   = lane >> 4;

    // XCD-chunked swizzle: consecutive tiles (adjacent wq) -> same XCD L2
    int bid  = blockIdx.x;
    int tile = (bid & 7) * 256 + (bid >> 3);
    int b  = tile >> 8;
    int hq = (tile >> 4) & 15;
    int wq = tile & 15;
    int h0 = hq * 8, w0 = wq * 8;

    s_bias[t]       = proj_b[256 + t];
    s_bias[256 + t] = proj_b[512 + t];

    // ---- stage x tile -> bf16 LDS, transposed [p][c], XOR swizzled ----
    {
        int cg  = t >> 4;            // 0..15
        int q4  = t & 15;
        int ph  = q4 >> 1, pw4 = (q4 & 1) * 4;
        const float* xbase = x + (size_t)(b * 256) * 16384 + (size_t)(h0 + ph) * 128 + (w0 + pw4);
#pragma unroll
        for (int i = 0; i < 16; ++i) {
            int c = i * 16 + cg;
            float4 v = *reinterpret_cast<const float4*>(xbase + (size_t)c * 16384);
            int pbase = ph * 8 + pw4;
            unsigned short hh[4] = {f2bf(v.x), f2bf(v.y), f2bf(v.z), f2bf(v.w)};
#pragma unroll
            for (int j = 0; j < 4; ++j) {
                int p = pbase + j;
                int off = p * 512 + ((2 * c) ^ ((p & 7) << 4));
                *reinterpret_cast<unsigned short*>(s_main + off) = hh[j];
            }
        }
    }
    __syncthreads();

    // ---- Q matvec: thread t computes qs[t] = scale*(W_q[t]·x[:,p0] + b[t]) ----
    {
        float qa = 0.f;
#pragma unroll 4
        for (int c8 = 0; c8 < 32; ++c8) {
            short8 xr = *reinterpret_cast<const short8*>(s_main + c8 * 16);  // row p=0, no swizzle
#pragma unroll
            for (int jj = 0; jj < 8; ++jj) {
                int c = c8 * 8 + jj;
                float xv = bf2f((unsigned short)xr[jj]);
                float wv = PRE ? bf2f(wpack[131072 + c * 256 + t]) : proj_w[t * 256 + c];
                qa += xv * wv;
            }
        }
        s_qs[t] = SCALE * (qa + proj_b[t]);
    }

    // ---- KV GEMM: wave owns kv rows [wave*128, wave*128+128) ----
    f32x4 acc[8][4];
#pragma unroll
    for (int mt = 0; mt < 8; ++mt)
#pragma unroll
        for (int nt = 0; nt < 4; ++nt) acc[mt][nt] = (f32x4){0.f, 0.f, 0.f, 0.f};

#pragma unroll 1
    for (int ks = 0; ks < 8; ++ks) {
        int k0 = ks * 32;
        short8 bfr[4];
#pragma unroll
        for (int nt = 0; nt < 4; ++nt) {
            int n  = nt * 16 + l15;
            int kb = k0 + l4 * 8;
            int off = n * 512 + ((2 * kb) ^ ((n & 7) << 4));
            bfr[nt] = *reinterpret_cast<const short8*>(s_main + off);
        }
#pragma unroll
        for (int mt = 0; mt < 8; ++mt) {
            short8 afr;
            if (PRE) {
                afr = *reinterpret_cast<const short8*>(
                    wpack + ((size_t)(((wave * 8 + mt) * 8 + ks) * 64 + lane)) * 8);
            } else {
                int row = 256 + wave * 128 + mt * 16 + l15;
                const float* wp2 = proj_w + row * 256 + k0 + l4 * 8;
                float4 a0 = *reinterpret_cast<const float4*>(wp2);
                float4 a1 = *reinterpret_cast<const float4*>(wp2 + 4);
                afr[0] = (short)f2bf(a0.x); afr[1] = (short)f2bf(a0.y);
                afr[2] = (short)f2bf(a0.z); afr[3] = (short)f2bf(a0.w);
                afr[4] = (short)f2bf(a1.x); afr[5] = (short)f2bf(a1.y);
                afr[6] = (short)f2bf(a1.z); afr[7] = (short)f2bf(a1.w);
            }
#pragma unroll
            for (int nt = 0; nt < 4; ++nt)
                acc[mt][nt] = __builtin_amdgcn_mfma_f32_16x16x32_bf16(afr, bfr[nt], acc[mt][nt], 0, 0, 0);
        }
    }
    __syncthreads();   // everyone done reading x tile

    // ---- waves 0,1: write key rows (+bias) to LDS [k=64][m=260] bf16 ----
    if (wave < 2) {
#pragma unroll
        for (int mt = 0; mt < 8; ++mt) {
            int m0 = wave * 128 + mt * 16 + l4 * 4;
#pragma unroll
            for (int nt = 0; nt < 4; ++nt) {
                int k = nt * 16 + l15;
                short4v hv;
#pragma unroll
                for (int i = 0; i < 4; ++i)
                    hv[i] = (short)f2bf(acc[mt][nt][i] + s_bias[m0 + i]);
                *reinterpret_cast<short4v*>(s_main + k * 520 + 2 * m0) = hv;
            }
        }
    }
    __syncthreads();

    // ---- logits + softmax: wave n0 handles heads n0 and n0+4; lane = key index ----
    {
        int n0 = wave, k = lane;
        float lg0 = 0.f, lg1 = 0.f;
#pragma unroll 4
        for (int d = 0; d < 32; ++d) {
            int o0 = n0 * 32 + d, o1 = o0 + 128;
            float q0 = s_qs[o0], q1 = s_qs[o1];
            float p0 = pos[o0 * 64 + k], p1 = pos[o1 * 64 + k];
            float v0 = bf2f(*reinterpret_cast<const unsigned short*>(s_main + k * 520 + 2 * o0));
            float v1 = bf2f(*reinterpret_cast<const unsigned short*>(s_main + k * 520 + 2 * o1));
            lg0 += q0 * (p0 + SCALE * v0);
            lg1 += q1 * (p1 + SCALE * v1);
        }
        float m0 = lg0, m1 = lg1;
#pragma unroll
        for (int off = 32; off >= 1; off >>= 1) {
            m0 = fmaxf(m0, __shfl_xor(m0, off));
            m1 = fmaxf(m1, __shfl_xor(m1, off));
        }
        float e0 = __expf(lg0 - m0), e1 = __expf(lg1 - m1);
        float s0 = e0, s1 = e1;
#pragma unroll
        for (int off = 32; off >= 1; off >>= 1) {
            s0 += __shfl_xor(s0, off);
            s1 += __shfl_xor(s1, off);
        }
        s_attn[n0 * 64 + k]       = e0 / s0;
        s_attn[(n0 + 4) * 64 + k] = e1 / s1;
    }
    __syncthreads();

    // ---- waves 2,3: out = attn @ val directly from accumulators ----
    // val row (vrow) = acc row; Σattn = 1 folds bias in additively.
    if (wave >= 2) {
        int voff = (wave - 2) * 128;
#pragma unroll
        for (int mt = 0; mt < 8; ++mt) {
            int head = (wave - 2) * 4 + (mt >> 1);
            const float* ap = s_attn + head * 64;
#pragma unroll
            for (int i = 0; i < 4; ++i) {
                float sum = 0.f;
#pragma unroll
                for (int nt = 0; nt < 4; ++nt)
                    sum += ap[nt * 16 + l15] * acc[mt][nt][i];
                sum += __shfl_xor(sum, 1);
                sum += __shfl_xor(sum, 2);
                sum += __shfl_xor(sum, 4);
                sum += __shfl_xor(sum, 8);
                if (l15 == 0) {
                    int vrow = voff + mt * 16 + l4 * 4 + i;
                    out[(size_t)b * 65536 + (size_t)vrow * 256 + hq * 16 + wq]
                        = sum + s_bias[256 + vrow];
                }
            }
        }
    }
}

extern "C" void kernel_launch(void* const* d_in, const int* in_sizes, int n_in,
                              void* d_out, int out_size, void* d_ws, size_t ws_size,
                              hipStream_t stream) {
    (void)in_sizes; (void)n_in; (void)out_size;
    const float* x      = (const float*)d_in[0];
    const float* proj_w = (const float*)d_in[1];
    const float* proj_b = (const float*)d_in[2];
    const float* pos    = (const float*)d_in[3];
    float* out = (float*)d_out;

    const size_t need_ws = 196608ull * sizeof(unsigned short);  // 384 KiB
    if (d_ws != nullptr && ws_size >= need_ws) {
        unsigned short* wp = (unsigned short*)d_ws;
        prepack_w<<<320, 256, 0, stream>>>(proj_w, wp);
        attn_fused<true><<<2048, 256, 0, stream>>>(x, proj_w, proj_b, pos, wp, out);
    } else {
        attn_fused<false><<<2048, 256, 0, stream>>>(x, proj_w, proj_b, pos, nullptr, out);
    }
}